// Round 14
// baseline (398.826 us; speedup 1.0000x reference)
//
#include <hip/hip_runtime.h>
#include <hip/hip_bf16.h>

#define NTOK   256
#define DMODEL 512
#define NHEAD  8
#define HD     64
#define HALF   32
#define FF     1536
#define RCFF   2048
#define VOCAB  32000
#define NLAYER 2
#define NSTEPS 4
#define EPSV   1e-6f
#define THR    0.99f

#define NTILE     (VOCAB / 64)          // 500 weight tiles
#define WT_MAT    (NTILE * DMODEL * 64) // shorts per matrix = 16,384,000
#define WT_OFF_F  5000000               // float offset of Wt in ws
#define WS_NEED   ((size_t)(WT_OFF_F + 2 * WT_MAT / 2) * 4)  // bytes

typedef __attribute__((ext_vector_type(8))) short bf16x8;
typedef __attribute__((ext_vector_type(4))) float f32x4;
typedef __attribute__((ext_vector_type(16))) float f32x16;

__device__ __forceinline__ short f2b(float x) {
    return (short)__hip_bfloat16_raw(__float2bfloat16(x)).x;
}

// ---------------- embedding gather + first rmsnorm fused ----------------
__global__ __launch_bounds__(256) void k_embed_norm(const int* __restrict__ ids,
                                                    const float* __restrict__ emb,
                                                    const float* __restrict__ w,
                                                    float* __restrict__ x,
                                                    float* __restrict__ xn) {
    int row = blockIdx.x, t = threadIdx.x;
    int id = ids[row];
    const float* er = emb + (size_t)id * DMODEL;
    float v0 = er[t], v1 = er[t + 256];
    float ss = v0 * v0 + v1 * v1;
    __shared__ float red[4];
    int lane = t & 63, wv = t >> 6;
    for (int o = 32; o > 0; o >>= 1) ss += __shfl_xor(ss, o);
    if (lane == 0) red[wv] = ss;
    __syncthreads();
    float tot = red[0] + red[1] + red[2] + red[3];
    float scale = rsqrtf(tot * (1.f / DMODEL) + EPSV);
    size_t base = (size_t)row * DMODEL;
    x[base + t] = v0;
    x[base + t + 256] = v1;
    xn[base + t] = v0 * scale * w[t];
    xn[base + t + 256] = v1 * scale * w[t + 256];
}

// ---------------- rmsnorm (one block per row) ----------------
__global__ __launch_bounds__(256) void k_rmsnorm(const float* __restrict__ in,
                                                 const float* __restrict__ w,
                                                 float* __restrict__ out) {
    int row = blockIdx.x;
    const float* xr = in + (size_t)row * DMODEL;
    float s = 0.f;
    for (int d = threadIdx.x; d < DMODEL; d += 256) { float v = xr[d]; s += v * v; }
    __shared__ float red[4];
    int lane = threadIdx.x & 63, wv = threadIdx.x >> 6;
    for (int o = 32; o > 0; o >>= 1) s += __shfl_xor(s, o);
    if (lane == 0) red[wv] = s;
    __syncthreads();
    float tot = red[0] + red[1] + red[2] + red[3];
    float scale = rsqrtf(tot * (1.f / DMODEL) + EPSV);
    for (int d = threadIdx.x; d < DMODEL; d += 256)
        out[(size_t)row * DMODEL + d] = xr[d] * scale * w[d];
}

// ---------------- split-K matmul partial (64x64 tile + register prefetch) ------
__global__ __launch_bounds__(256) void k_mm_part(const float* __restrict__ A,
                                                 const float* __restrict__ W,
                                                 float* __restrict__ Cp,
                                                 int K, int N, int kc) {
    __shared__ float As[16][68];
    __shared__ float Ws[16][68];
    const int bn = blockIdx.x * 64;
    const int bm = blockIdx.y * 64;
    const int kz = blockIdx.z * kc;
    const int tx = threadIdx.x & 15;
    const int ty = threadIdx.x >> 4;
    float ar[4], wr[4];
#pragma unroll
    for (int r = 0; r < 4; ++r) {
        int idx = threadIdx.x + r * 256;
        int m = idx >> 4, kk = idx & 15;
        ar[r] = A[(size_t)(bm + m) * K + kz + kk];
        int n = idx & 63, kw = idx >> 6;
        wr[r] = W[(size_t)(kz + kw) * N + bn + n];
    }
    float acc[4][4] = {};
    for (int k0 = kz; k0 < kz + kc; k0 += 16) {
#pragma unroll
        for (int r = 0; r < 4; ++r) {
            int idx = threadIdx.x + r * 256;
            int m = idx >> 4, kk = idx & 15;
            As[kk][m] = ar[r];
            int n = idx & 63, kw = idx >> 6;
            Ws[kw][n] = wr[r];
        }
        __syncthreads();
        if (k0 + 16 < kz + kc) {   // prefetch next chunk into registers
#pragma unroll
            for (int r = 0; r < 4; ++r) {
                int idx = threadIdx.x + r * 256;
                int m = idx >> 4, kk = idx & 15;
                ar[r] = A[(size_t)(bm + m) * K + k0 + 16 + kk];
                int n = idx & 63, kw = idx >> 6;
                wr[r] = W[(size_t)(k0 + 16 + kw) * N + bn + n];
            }
        }
#pragma unroll
        for (int kk = 0; kk < 16; ++kk) {
            float4 av = *(const float4*)&As[kk][ty * 4];
            float4 bv = *(const float4*)&Ws[kk][tx * 4];
            float a[4] = {av.x, av.y, av.z, av.w};
            float b[4] = {bv.x, bv.y, bv.z, bv.w};
#pragma unroll
            for (int i = 0; i < 4; ++i)
#pragma unroll
                for (int j = 0; j < 4; ++j)
                    acc[i][j] = fmaf(a[i], b[j], acc[i][j]);
        }
        __syncthreads();
    }
    float* cp = Cp + (size_t)blockIdx.z * (size_t)(gridDim.y * 64) * N;
#pragma unroll
    for (int i = 0; i < 4; ++i) {
        int m = bm + ty * 4 + i;
#pragma unroll
        for (int j = 0; j < 4; ++j)
            cp[(size_t)m * N + bn + tx * 4 + j] = acc[i][j];
    }
}

// ---------------- gate+up combined split-K partial: 4 slices + prefetch --------
__global__ __launch_bounds__(256) void k_gu_part(const float* __restrict__ A,
                                                 const float* __restrict__ Wg,
                                                 const float* __restrict__ Wu,
                                                 float* __restrict__ GU) {
    __shared__ float As[16][68];
    __shared__ float Ws[16][68];
    const int bn = blockIdx.x * 64;
    const int bm = blockIdx.y * 64;
    const int z = blockIdx.z;
    const float* W = (z >> 1) ? Wu : Wg;
    const int kz = (z & 1) * 256;
    const int tx = threadIdx.x & 15;
    const int ty = threadIdx.x >> 4;
    float ar[4], wr[4];
#pragma unroll
    for (int r = 0; r < 4; ++r) {
        int idx = threadIdx.x + r * 256;
        int m = idx >> 4, kk = idx & 15;
        ar[r] = A[(size_t)(bm + m) * DMODEL + kz + kk];
        int n = idx & 63, kw = idx >> 6;
        wr[r] = W[(size_t)(kz + kw) * FF + bn + n];
    }
    float acc[4][4] = {};
    for (int k0 = kz; k0 < kz + 256; k0 += 16) {
#pragma unroll
        for (int r = 0; r < 4; ++r) {
            int idx = threadIdx.x + r * 256;
            int m = idx >> 4, kk = idx & 15;
            As[kk][m] = ar[r];
            int n = idx & 63, kw = idx >> 6;
            Ws[kw][n] = wr[r];
        }
        __syncthreads();
        if (k0 + 16 < kz + 256) {
#pragma unroll
            for (int r = 0; r < 4; ++r) {
                int idx = threadIdx.x + r * 256;
                int m = idx >> 4, kk = idx & 15;
                ar[r] = A[(size_t)(bm + m) * DMODEL + k0 + 16 + kk];
                int n = idx & 63, kw = idx >> 6;
                wr[r] = W[(size_t)(k0 + 16 + kw) * FF + bn + n];
            }
        }
#pragma unroll
        for (int kk = 0; kk < 16; ++kk) {
            float4 av = *(const float4*)&As[kk][ty * 4];
            float4 bv = *(const float4*)&Ws[kk][tx * 4];
            float a[4] = {av.x, av.y, av.z, av.w};
            float b[4] = {bv.x, bv.y, bv.z, bv.w};
#pragma unroll
            for (int i = 0; i < 4; ++i)
#pragma unroll
                for (int j = 0; j < 4; ++j)
                    acc[i][j] = fmaf(a[i], b[j], acc[i][j]);
        }
        __syncthreads();
    }
    float* cp = GU + (size_t)z * (NTOK * FF);
#pragma unroll
    for (int i = 0; i < 4; ++i) {
        int m = bm + ty * 4 + i;
#pragma unroll
        for (int j = 0; j < 4; ++j)
            cp[(size_t)m * FF + bn + tx * 4 + j] = acc[i][j];
    }
}

// ---------------- split-K elementwise reduce (+optional gelu) ----------------
__global__ void k_mm_finish(const float* __restrict__ Cp, const float* __restrict__ res,
                            float* __restrict__ C, int tot, int zstride, int nz, int act) {
    int i = blockIdx.x * 256 + threadIdx.x;
    if (i >= tot) return;
    float s = 0.f;
    for (int z = 0; z < nz; ++z) s += Cp[(size_t)z * zstride + i];
    if (res) s += res[i];
    if (act == 1) {  // gelu (tanh approx, jax default)
        float xg = s;
        float inner = 0.79788456080286536f * (xg + 0.044715f * xg * xg * xg);
        s = 0.5f * xg * (1.f + tanhf(inner));
    }
    C[i] = s;
}

// ---------------- reduce + silu(g)*u  (gate z=0..1, up z=2..3) ----------------
__global__ void k_finish_silumul(const float* __restrict__ GU, float* __restrict__ C) {
    int i = blockIdx.x * 256 + threadIdx.x;   // tot = 256*1536
    float g = GU[i] + GU[(size_t)(NTOK * FF) + i];
    float u = GU[(size_t)(2 * NTOK * FF) + i] + GU[(size_t)(3 * NTOK * FF) + i];
    float sig = 1.f / (1.f + expf(-g));
    C[i] = g * sig * u;
}

// ---------------- reduce + residual + dual write (raw, rmsnorm) ----------------
__global__ __launch_bounds__(256) void k_finish_norm(const float* __restrict__ Cp,
                                                     const float* __restrict__ res,
                                                     const float* __restrict__ normw,
                                                     float* __restrict__ out_raw,
                                                     float* __restrict__ out_norm,
                                                     int nz) {
    int row = blockIdx.x, t = threadIdx.x;
    int c0 = t, c1 = t + 256;
    size_t base = (size_t)row * DMODEL;
    float v0 = 0.f, v1 = 0.f;
    for (int z = 0; z < nz; ++z) {
        size_t zb = (size_t)z * (NTOK * DMODEL) + base;
        v0 += Cp[zb + c0];
        v1 += Cp[zb + c1];
    }
    v0 += res[base + c0];
    v1 += res[base + c1];
    float ss = v0 * v0 + v1 * v1;
    __shared__ float red[4];
    int lane = t & 63, wv = t >> 6;
    for (int o = 32; o > 0; o >>= 1) ss += __shfl_xor(ss, o);
    if (lane == 0) red[wv] = ss;
    __syncthreads();
    float tot = red[0] + red[1] + red[2] + red[3];
    float scale = rsqrtf(tot * (1.f / DMODEL) + EPSV);
    out_raw[base + c0] = v0;
    out_raw[base + c1] = v1;
    out_norm[base + c0] = v0 * scale * normw[c0];
    out_norm[base + c1] = v1 * scale * normw[c1];
}

// ---------------- qkv reduce + RoPE fused (z=4 slices, N=1536) ----------------
__global__ __launch_bounds__(256) void k_qkv_finish_rope(const float* __restrict__ Cp,
                                                         float* __restrict__ qkv) {
    int pos = blockIdx.x, t = threadIdx.x;
    int h = t >> 5, d = t & 31;
    size_t base = (size_t)pos * FF;
    auto S = [&](int col) {
        float s = 0.f;
#pragma unroll
        for (int z = 0; z < 4; ++z) s += Cp[(size_t)z * (NTOK * FF) + base + col];
        return s;
    };
    int cq0 = h * HD + d, cq1 = cq0 + HALF;
    int ck0 = DMODEL + cq0, ck1 = ck0 + HALF;
    int cv0 = 2 * DMODEL + t, cv1 = cv0 + 256;
    float q0 = S(cq0), q1 = S(cq1);
    float k0 = S(ck0), k1 = S(ck1);
    float v0 = S(cv0), v1 = S(cv1);
    float inv = powf(10000.f, -(float)d / 32.f);
    float ang = (float)pos * inv;
    float c = cosf(ang), s = sinf(ang);
    qkv[base + cq0] = q0 * c - q1 * s;
    qkv[base + cq1] = q0 * s + q1 * c;
    qkv[base + ck0] = k0 * c - k1 * s;
    qkv[base + ck1] = k0 * s + k1 * c;
    qkv[base + cv0] = v0;
    qkv[base + cv1] = v1;
}

// ---------------- attention: one block per (head, query) ----------------
__global__ __launch_bounds__(256) void k_attn(const float* __restrict__ qkv,
                                              float* __restrict__ out) {
    int h = blockIdx.x;
    int qi = blockIdx.y;
    int t = threadIdx.x;
    __shared__ float qs[HD];
    __shared__ float ps[NTOK];
    __shared__ float red[4];
    __shared__ float red2[4];
    __shared__ float os[4][HD];
    if (t < HD) qs[t] = qkv[(size_t)qi * FF + h * HD + t];
    __syncthreads();
    float sc = -1e30f;
    if (t <= qi) {
        const float* kr = qkv + (size_t)t * FF + DMODEL + h * HD;
        float s = 0.f;
        for (int d = 0; d < HD; ++d) s = fmaf(qs[d], kr[d], s);
        sc = s * 0.125f;
    }
    float m = sc;
    for (int o = 32; o > 0; o >>= 1) m = fmaxf(m, __shfl_xor(m, o));
    int lane = t & 63, wv = t >> 6;
    if (lane == 0) red[wv] = m;
    __syncthreads();
    m = fmaxf(fmaxf(red[0], red[1]), fmaxf(red[2], red[3]));
    float e = (t <= qi) ? expf(sc - m) : 0.f;
    ps[t] = e;
    float sum = e;
    for (int o = 32; o > 0; o >>= 1) sum += __shfl_xor(sum, o);
    if (lane == 0) red2[wv] = sum;
    __syncthreads();
    sum = red2[0] + red2[1] + red2[2] + red2[3];
    float inv = 1.f / sum;
    int d = t & 63, g = t >> 6;
    float acc = 0.f;
    for (int ki = g; ki <= qi; ki += 4)
        acc = fmaf(ps[ki], qkv[(size_t)ki * FF + 2 * DMODEL + h * HD + d], acc);
    os[g][d] = acc * inv;
    __syncthreads();
    if (t < HD)
        out[(size_t)qi * DMODEL + h * HD + t] = os[0][t] + os[1][t] + os[2][t] + os[3][t];
}

// ---------------- halt dots + ACT combine + A/B build, one block per token ----
__global__ __launch_bounds__(256) void k_haltactab(const float* __restrict__ H,
                                                   const float* __restrict__ wh,
                                                   const float* __restrict__ bptr,
                                                   float* __restrict__ ponder_out,
                                                   float* __restrict__ w_out,
                                                   __hip_bfloat16* __restrict__ A,
                                                   __hip_bfloat16* __restrict__ Bm) {
    int i = blockIdx.x, t = threadIdx.x;
    int lane = t & 63, wv = t >> 6;
    __shared__ float red[4];
    __shared__ float hvals[3];
    __shared__ float hw[4];
    for (int s = 1; s <= 3; ++s) {
        const float* hr = H + ((size_t)s * NTOK + i) * DMODEL;
        float a = hr[t] * wh[t] + hr[t + 256] * wh[t + 256];
        for (int o = 32; o > 0; o >>= 1) a += __shfl_xor(a, o);
        if (lane == 0) red[wv] = a;
        __syncthreads();
        if (t == 0)
            hvals[s - 1] = 1.f / (1.f + expf(-(red[0] + red[1] + red[2] + red[3] + bptr[0])));
        __syncthreads();
    }
    if (t == 0) {
        float p[4] = {0.f, hvals[0], hvals[1], hvals[2]};
        float cum = 0.f, rem = 0.f;
        int nrun = 0;
#pragma unroll
        for (int s = 0; s < 4; ++s) {
            float prev = cum;
            cum += p[s];
            bool running = prev < THR;
            bool use_rem = running && ((cum >= THR) || (s == 3));
            float v = 0.f;
            if (running) {
                v = use_rem ? (1.f - prev) : p[s];
                if (use_rem) rem += (1.f - prev);
                nrun++;
            }
            hw[s] = v;
            w_out[i * 4 + s] = v;
        }
        ponder_out[i] = (float)nrun + rem;
    }
    __syncthreads();
    float w0 = hw[0], w1 = hw[1], w2 = hw[2], w3 = hw[3];
    size_t base = (size_t)i * DMODEL;
#pragma unroll
    for (int r = 0; r < 2; ++r) {
        int d = t + r * 256;
        float h0 = H[base + d];
        float h1 = H[(size_t)(NTOK * DMODEL) + base + d];
        float h2 = H[(size_t)(2 * NTOK * DMODEL) + base + d];
        float h3 = H[(size_t)(3 * NTOK * DMODEL) + base + d];
        float h4 = H[(size_t)(4 * NTOK * DMODEL) + base + d];
        A[base + d]  = __float2bfloat16(w0 * h0 + w1 * h1 + w2 * h2 + w3 * h3);
        Bm[base + d] = __float2bfloat16(w0 * h1 + w1 * h2 + w2 * h3 + w3 * h4);
    }
}

// ---------------- weight f32 -> bf16 fragment-tiled conversion ----------------
// Wt[mat][T][kg][c][j] = bf16(W[kg*8+j][T*64+c]); per-tile chunk [kg][c][j] so a
// lane's MFMA B-fragment (col c, k=kg*8+j) is one contiguous bf16x8 and a wave's
// 32 lanes read 512B contiguous. Reads: 1KB/row coalesced; writes: 4KB chunks.
__global__ __launch_bounds__(256) void k_wconv(const float* __restrict__ Wy,
                                               const float* __restrict__ Wd,
                                               short* __restrict__ Wt) {
    __shared__ short tl[4 * 2048];   // 16 KB: 4 tiles x [32k][64c]
    const int t = threadIdx.x;
    const int cb = blockIdx.x * 256;
    const int kb = blockIdx.y * 32;
    const int mat = blockIdx.z;
    const float* W = mat ? Wd : Wy;
#pragma unroll
    for (int p = 0; p < 8; ++p) {
        int row = kb + p * 4 + (t >> 6);
        int col = cb + (t & 63) * 4;
        float4 v = *(const float4*)&W[(size_t)row * VOCAB + col];
        int ti = (t & 63) >> 4;
        int ci = ((t & 63) * 4) & 63;
        int ri = p * 4 + (t >> 6);
        short4 s;
        s.x = f2b(v.x); s.y = f2b(v.y); s.z = f2b(v.z); s.w = f2b(v.w);
        *(short4*)&tl[ti * 2048 + ri * 64 + ci] = s;
    }
    __syncthreads();
    // write: per tile a contiguous 2048-short chunk; permuted [kg][c][j] inside.
    // thread t covers (kgl = t>>6, ci = t&63), j=0..7; dst_local = t*8 + j.
#pragma unroll
    for (int ti = 0; ti < 4; ++ti) {
        size_t doff = (size_t)mat * WT_MAT + (size_t)(cb / 64 + ti) * (DMODEL * 64)
                    + (size_t)(kb / 8) * 512 + t * 8;
        short v[8];
#pragma unroll
        for (int j = 0; j < 8; ++j)
            v[j] = tl[ti * 2048 + ((t >> 6) * 8 + j) * 64 + (t & 63)];
        *(bf16x8*)&Wt[doff] = *(bf16x8*)v;
    }
}

// ---------------- final logits: 32x32x16 MFMA, fragment-direct bf16 weights ----
// Weights read straight from L3-resident Wt (no weight LDS, no convert); acts
// staged via LDS exactly as the verified round-13 kernel. Same MFMA mapping.
__global__ __launch_bounds__(512) void k_logits_bf16t(const __hip_bfloat16* __restrict__ Abf,
                                                      const __hip_bfloat16* __restrict__ Bbf,
                                                      const short* __restrict__ Wt,
                                                      float* __restrict__ out) {
    __shared__ short Alds[256 * 40];
    __shared__ short Blds[256 * 40];
    const int tid  = threadIdx.x;
    const int wave = tid >> 6;
    const int lane = tid & 63;
    const int l31  = lane & 31;
    const int hi8  = (lane >> 5) * 8;
    const int wv_row = (wave & 3) * 64;
    const int wv_col = (wave >> 2) * 32;

    const int sr0 = tid >> 2;
    const int skp = (tid & 3) * 8;

    f32x16 acc0 = {};
    f32x16 acc1 = {};

    // weight fragment base: Wt[mat][T][kg][colg][j]; kg = k/8 = k0/8 + h*2 + (lane>>5)
    const size_t wbase = (size_t)blockIdx.x * (DMODEL * 64)
                       + (size_t)(wv_col + l31) * 8 + (size_t)(lane >> 5) * 512;
    const short* wy = Wt + wbase;
    const short* wd = Wt + (size_t)WT_MAT + wbase;

    bf16x8 cwy0 = *(const bf16x8*)(wy);              // h=0: kg offset 0
    bf16x8 cwy1 = *(const bf16x8*)(wy + 2 * 512);    // h=1: +2 kg
    bf16x8 cwd0 = *(const bf16x8*)(wd);
    bf16x8 cwd1 = *(const bf16x8*)(wd + 2 * 512);
    bf16x8 ra0 = *(const bf16x8*)(Abf + (size_t)sr0 * DMODEL + skp);
    bf16x8 ra1 = *(const bf16x8*)(Abf + (size_t)(sr0 + 128) * DMODEL + skp);
    bf16x8 rb0 = *(const bf16x8*)(Bbf + (size_t)sr0 * DMODEL + skp);
    bf16x8 rb1 = *(const bf16x8*)(Bbf + (size_t)(sr0 + 128) * DMODEL + skp);

    for (int t = 0; t < 16; ++t) {
        __syncthreads();  // previous iteration's act-fragment reads complete
        *(bf16x8*)&Alds[sr0 * 40 + skp]         = ra0;
        *(bf16x8*)&Alds[(sr0 + 128) * 40 + skp] = ra1;
        *(bf16x8*)&Blds[sr0 * 40 + skp]         = rb0;
        *(bf16x8*)&Blds[(sr0 + 128) * 40 + skp] = rb1;
        bf16x8 nwy0, nwy1, nwd0, nwd1;
        if (t < 15) {  // prefetch next 32-k tile (acts + weights)
            const int kn = (t + 1) * 32;
            const size_t kgoff = (size_t)(kn / 8) * 512;
            nwy0 = *(const bf16x8*)(wy + kgoff);
            nwy1 = *(const bf16x8*)(wy + kgoff + 2 * 512);
            nwd0 = *(const bf16x8*)(wd + kgoff);
            nwd1 = *(const bf16x8*)(wd + kgoff + 2 * 512);
            ra0 = *(const bf16x8*)(Abf + (size_t)sr0 * DMODEL + kn + skp);
            ra1 = *(const bf16x8*)(Abf + (size_t)(sr0 + 128) * DMODEL + kn + skp);
            rb0 = *(const bf16x8*)(Bbf + (size_t)sr0 * DMODEL + kn + skp);
            rb1 = *(const bf16x8*)(Bbf + (size_t)(sr0 + 128) * DMODEL + kn + skp);
        }
        __syncthreads();  // act tile visible
        {   // h = 0 (k = hi8 .. within first 16)
            const int klo = hi8;
            const bf16x8 ay0 = *(const bf16x8*)&Alds[(wv_row + l31) * 40 + klo];
            const bf16x8 ay1 = *(const bf16x8*)&Alds[(wv_row + 32 + l31) * 40 + klo];
            const bf16x8 ad0 = *(const bf16x8*)&Blds[(wv_row + l31) * 40 + klo];
            const bf16x8 ad1 = *(const bf16x8*)&Blds[(wv_row + 32 + l31) * 40 + klo];
            acc0 = __builtin_amdgcn_mfma_f32_32x32x16_bf16(ay0, cwy0, acc0, 0, 0, 0);
            acc0 = __builtin_amdgcn_mfma_f32_32x32x16_bf16(ad0, cwd0, acc0, 0, 0, 0);
            acc1 = __builtin_amdgcn_mfma_f32_32x32x16_bf16(ay1, cwy0, acc1, 0, 0, 0);
            acc1 = __builtin_amdgcn_mfma_f32_32x32x16_bf16(ad1, cwd0, acc1, 0, 0, 0);
        }
        {   // h = 1
            const int klo = 16 + hi8;
            const bf16x8 ay0 = *(const bf16x8*)&Alds[(wv_row + l31) * 40 + klo];
            const bf16x8 ay1 = *(const bf16x8*)&Alds[(wv_row + 32 + l31) * 40 + klo];
            const bf16x8 ad0 = *(const bf16x8*)&Blds[(wv_row + l31) * 40 + klo];
            const bf16x8 ad1 = *(const bf16x8*)&Blds[(wv_row + 32 + l31) * 40 + klo];
            acc0 = __builtin_amdgcn_mfma_f32_32x32x16_bf16(ay0, cwy1, acc0, 0, 0, 0);
            acc0 = __builtin_amdgcn_mfma_f32_32x32x16_bf16(ad0, cwd1, acc0, 0, 0, 0);
            acc1 = __builtin_amdgcn_mfma_f32_32x32x16_bf16(ay1, cwy1, acc1, 0, 0, 0);
            acc1 = __builtin_amdgcn_mfma_f32_32x32x16_bf16(ad1, cwd1, acc1, 0, 0, 0);
        }
        cwy0 = nwy0; cwy1 = nwy1; cwd0 = nwd0; cwd1 = nwd1;
    }
    // C/D layout (verified): col = lane&31, row = (reg&3) + 8*(reg>>2) + 4*(lane>>5)
    const int col = blockIdx.x * 64 + wv_col + l31;
    const int rbase = (lane >> 5) * 4;
#pragma unroll
    for (int reg = 0; reg < 16; ++reg) {
        int rowin = (reg & 3) + 8 * (reg >> 2) + rbase;
        out[(size_t)(wv_row + rowin) * VOCAB + col] = acc0[reg];
        out[(size_t)(wv_row + 32 + rowin) * VOCAB + col] = acc1[reg];
    }
}

// ---------------- fallback logits (round-13, proven) ----------------
__global__ __launch_bounds__(512) void k_logits_mfma(const __hip_bfloat16* __restrict__ Abf,
                                                     const __hip_bfloat16* __restrict__ Bbf,
                                                     const float* __restrict__ Wy,
                                                     const float* __restrict__ Wd,
                                                     float* __restrict__ out) {
    __shared__ short Alds[256 * 40];
    __shared__ short Blds[256 * 40];
    __shared__ short Wys[64 * 40];
    __shared__ short Wds[64 * 40];
    const int tid  = threadIdx.x;
    const int wave = tid >> 6;
    const int lane = tid & 63;
    const int l31  = lane & 31;
    const int hi8  = (lane >> 5) * 8;
    const int wv_row = (wave & 3) * 64;
    const int wv_col = (wave >> 2) * 32;
    const int sr0 = tid >> 2;
    const int skp = (tid & 3) * 8;
    const int wc  = tid & 63;
    const int wk4 = (tid >> 6) * 4;
    f32x16 acc0 = {};
    f32x16 acc1 = {};
    const size_t woff = (size_t)wk4 * VOCAB + blockIdx.x * 64 + wc;
    const float* gy = Wy + woff;
    const float* gd = Wd + woff;
    float rys[4], rds[4];
#pragma unroll
    for (int j = 0; j < 4; ++j) {
        rys[j] = gy[(size_t)j * VOCAB];
        rds[j] = gd[(size_t)j * VOCAB];
    }
    bf16x8 ra0 = *(const bf16x8*)(Abf + (size_t)sr0 * DMODEL + skp);
    bf16x8 ra1 = *(const bf16x8*)(Abf + (size_t)(sr0 + 128) * DMODEL + skp);
    bf16x8 rb0 = *(const bf16x8*)(Bbf + (size_t)sr0 * DMODEL + skp);
    bf16x8 rb1 = *(const bf16x8*)(Bbf + (size_t)(sr0 + 128) * DMODEL + skp);
    for (int t = 0; t < 16; ++t) {
        __syncthreads();
        {
            short4 sy, sd;
            sy.x = f2b(rys[0]); sy.y = f2b(rys[1]); sy.z = f2b(rys[2]); sy.w = f2b(rys[3]);
            sd.x = f2b(rds[0]); sd.y = f2b(rds[1]); sd.z = f2b(rds[2]); sd.w = f2b(rds[3]);
            *(short4*)&Wys[wc * 40 + wk4] = sy;
            *(short4*)&Wds[wc * 40 + wk4] = sd;
            *(bf16x8*)&Alds[sr0 * 40 + skp]         = ra0;
            *(bf16x8*)&Alds[(sr0 + 128) * 40 + skp] = ra1;
            *(bf16x8*)&Blds[sr0 * 40 + skp]         = rb0;
            *(bf16x8*)&Blds[(sr0 + 128) * 40 + skp] = rb1;
        }
        if (t < 15) {
            const int kn = (t + 1) * 32;
            const float* gy2 = gy + (size_t)kn * VOCAB;
            const float* gd2 = gd + (size_t)kn * VOCAB;
#pragma unroll
            for (int j = 0; j < 4; ++j) {
                rys[j] = gy2[(size_t)j * VOCAB];
                rds[j] = gd2[(size_t)j * VOCAB];
            }
            ra0 = *(const bf16x8*)(Abf + (size_t)sr0 * DMODEL + kn + skp);
            ra1 = *(const bf16x8*)(Abf + (size_t)(sr0 + 128) * DMODEL + kn + skp);
            rb0 = *(const bf16x8*)(Bbf + (size_t)sr0 * DMODEL + kn + skp);
            rb1 = *(const bf16x8*)(Bbf + (size_t)(sr0 + 128) * DMODEL + kn + skp);
        }
        __syncthreads();
#pragma unroll
        for (int h = 0; h < 2; ++h) {
            const int klo = h * 16 + hi8;
            const bf16x8 wyf = *(const bf16x8*)&Wys[(wv_col + l31) * 40 + klo];
            const bf16x8 wdf = *(const bf16x8*)&Wds[(wv_col + l31) * 40 + klo];
            const bf16x8 ay0 = *(const bf16x8*)&Alds[(wv_row + l31) * 40 + klo];
            const bf16x8 ay1 = *(const bf16x8*)&Alds[(wv_row + 32 + l31) * 40 + klo];
            const bf16x8 ad0 = *(const bf16x8*)&Blds[(wv_row + l31) * 40 + klo];
            const bf16x8 ad1 = *(const bf16x8*)&Blds[(wv_row + 32 + l31) * 40 + klo];
            acc0 = __builtin_amdgcn_mfma_f32_32x32x16_bf16(ay0, wyf, acc0, 0, 0, 0);
            acc0 = __builtin_amdgcn_mfma_f32_32x32x16_bf16(ad0, wdf, acc0, 0, 0, 0);
            acc1 = __builtin_amdgcn_mfma_f32_32x32x16_bf16(ay1, wyf, acc1, 0, 0, 0);
            acc1 = __builtin_amdgcn_mfma_f32_32x32x16_bf16(ad1, wdf, acc1, 0, 0, 0);
        }
    }
    const int col = blockIdx.x * 64 + wv_col + l31;
    const int rbase = (lane >> 5) * 4;
#pragma unroll
    for (int reg = 0; reg < 16; ++reg) {
        int rowin = (reg & 3) + 8 * (reg >> 2) + rbase;
        out[(size_t)(wv_row + rowin) * VOCAB + col] = acc0[reg];
        out[(size_t)(wv_row + 32 + rowin) * VOCAB + col] = acc1[reg];
    }
}

extern "C" void kernel_launch(void* const* d_in, const int* in_sizes, int n_in,
                              void* d_out, int out_size, void* d_ws, size_t ws_size,
                              hipStream_t stream) {
    const int*   ids          = (const int*)d_in[0];
    const float* emb          = (const float*)d_in[1];
    const float* attn_norm_w  = (const float*)d_in[2];
    const float* mlp_norm_w   = (const float*)d_in[3];
    const float* wqkv         = (const float*)d_in[4];
    const float* wo           = (const float*)d_in[5];
    const float* w_gate       = (const float*)d_in[6];
    const float* w_up         = (const float*)d_in[7];
    const float* w_down       = (const float*)d_in[8];
    const float* final_norm_w = (const float*)d_in[9];
    const float* rc_norm_w    = (const float*)d_in[10];
    const float* rc_w1        = (const float*)d_in[11];
    const float* rc_w2        = (const float*)d_in[12];
    const float* w_y          = (const float*)d_in[13];
    const float* w_delta      = (const float*)d_in[14];
    const float* w_halt       = (const float*)d_in[15];
    const float* b_halt       = (const float*)d_in[16];
    float* out = (float*)d_out;

    float* ws = (float*)d_ws;
    // Live-range map (floats) — identical to rounds 10-13 (proven):
    //   x 0.. | xn 131072.. | qkv 262144.. | attnout 655360.. | g 786432..
    //   t1 1179648.. | states 1703936.. | states2 1835008.. | H 1966080..
    //   Abf 2623488.. | Bbf 2754560.. | Cp 2885632..4982784 | GU 1179648.. (backbone)
    //   Wt (bf16 tiled weights) 5000000.. (gated on ws_size)
    float* x       = ws + 0;
    float* xn      = ws + 131072;
    float* qkv     = ws + 262144;
    float* attnout = ws + 655360;
    float* g       = ws + 786432;
    float* t1      = ws + 1179648;
    float* states  = ws + 1703936;
    float* states2 = ws + 1835008;
    float* H       = ws + 1966080;
    __hip_bfloat16* Abf = (__hip_bfloat16*)(ws + 2623488);
    __hip_bfloat16* Bbf = (__hip_bfloat16*)(ws + 2754560);
    float* Cp      = ws + 2885632;
    float* GU      = ws + 1179648;
    short* Wt      = (short*)(ws + WT_OFF_F);
    const bool use_bf16t = (ws_size >= WS_NEED);

    // ---------- weight conversion (independent of everything else) ----------
    if (use_bf16t)
        k_wconv<<<dim3(VOCAB / 256, DMODEL / 32, 2), 256, 0, stream>>>(w_y, w_delta, Wt);

    // ---------- backbone ----------
    k_embed_norm<<<NTOK, 256, 0, stream>>>(ids, emb, attn_norm_w, x, xn);
    for (int l = 0; l < NLAYER; ++l) {
        k_mm_part<<<dim3(FF / 64, 4, 4), 256, 0, stream>>>(
            xn, wqkv + (size_t)l * DMODEL * FF, Cp, DMODEL, FF, 128);
        k_qkv_finish_rope<<<NTOK, 256, 0, stream>>>(Cp, qkv);
        k_attn<<<dim3(NHEAD, NTOK), 256, 0, stream>>>(qkv, attnout);
        k_mm_part<<<dim3(DMODEL / 64, 4, 8), 256, 0, stream>>>(
            attnout, wo + (size_t)l * DMODEL * DMODEL, Cp, DMODEL, DMODEL, 64);
        k_finish_norm<<<NTOK, 256, 0, stream>>>(Cp, x, mlp_norm_w + l * DMODEL, x, xn, 8);
        k_gu_part<<<dim3(FF / 64, 4, 4), 256, 0, stream>>>(
            xn, w_gate + (size_t)l * DMODEL * FF, w_up + (size_t)l * DMODEL * FF, GU);
        k_finish_silumul<<<NTOK * FF / 256, 256, 0, stream>>>(GU, g);
        k_mm_part<<<dim3(DMODEL / 64, 4, 12), 256, 0, stream>>>(
            g, w_down + (size_t)l * FF * DMODEL, Cp, FF, DMODEL, 128);
        const float* nw = (l == 0) ? (attn_norm_w + DMODEL) : final_norm_w;
        float* nout = (l == 0) ? xn : states;
        k_finish_norm<<<NTOK, 256, 0, stream>>>(Cp, x, nw, x, nout, 12);
    }

    // ---------- refinement steps (halt path stays f32) ----------
    k_rmsnorm<<<NTOK, 256, 0, stream>>>(states, rc_norm_w, H);
    float* scur = states;
    float* snxt = states2;
    for (int s = 0; s < NSTEPS; ++s) {
        k_mm_part<<<dim3(RCFF / 64, 4, 4), 256, 0, stream>>>(
            H + (size_t)s * NTOK * DMODEL, rc_w1, Cp, DMODEL, RCFF, 128);
        k_mm_finish<<<NTOK * RCFF / 256, 256, 0, stream>>>(
            Cp, nullptr, t1, NTOK * RCFF, NTOK * RCFF, 4, 1);
        k_mm_part<<<dim3(DMODEL / 64, 4, 16), 256, 0, stream>>>(
            t1, rc_w2, Cp, RCFF, DMODEL, 128);
        k_finish_norm<<<NTOK, 256, 0, stream>>>(
            Cp, scur, rc_norm_w, snxt, H + (size_t)(s + 1) * NTOK * DMODEL, 16);
        float* tmp = scur; scur = snxt; snxt = tmp;
    }

    // ---------- halt + ACT + A/B in one kernel ----------
    k_haltactab<<<NTOK, 256, 0, stream>>>(H, w_halt, b_halt,
                                          out + (size_t)NTOK * VOCAB,
                                          out + (size_t)NTOK * VOCAB + NTOK,
                                          Abf, Bbf);

    // ---------- final logits ----------
    if (use_bf16t)
        k_logits_bf16t<<<NTILE, 512, 0, stream>>>(Abf, Bbf, Wt, out);
    else
        k_logits_mfma<<<NTILE, 512, 0, stream>>>(Abf, Bbf, w_y, w_delta, out);
}

// Round 15
// 374.964 us; speedup vs baseline: 1.0636x; 1.0636x over previous
//
#include <hip/hip_runtime.h>
#include <hip/hip_bf16.h>

#define NTOK   256
#define DMODEL 512
#define NHEAD  8
#define HD     64
#define HALF   32
#define FF     1536
#define RCFF   2048
#define VOCAB  32000
#define NLAYER 2
#define NSTEPS 4
#define EPSV   1e-6f
#define THR    0.99f

typedef __attribute__((ext_vector_type(8))) short bf16x8;
typedef __attribute__((ext_vector_type(4))) float f32x4;
typedef __attribute__((ext_vector_type(16))) float f32x16;

__device__ __forceinline__ short f2b(float x) {
    return (short)__hip_bfloat16_raw(__float2bfloat16(x)).x;
}

// ---------------- embedding gather + first rmsnorm fused ----------------
__global__ __launch_bounds__(256) void k_embed_norm(const int* __restrict__ ids,
                                                    const float* __restrict__ emb,
                                                    const float* __restrict__ w,
                                                    float* __restrict__ x,
                                                    float* __restrict__ xn) {
    int row = blockIdx.x, t = threadIdx.x;
    int id = ids[row];
    const float* er = emb + (size_t)id * DMODEL;
    float v0 = er[t], v1 = er[t + 256];
    float ss = v0 * v0 + v1 * v1;
    __shared__ float red[4];
    int lane = t & 63, wv = t >> 6;
    for (int o = 32; o > 0; o >>= 1) ss += __shfl_xor(ss, o);
    if (lane == 0) red[wv] = ss;
    __syncthreads();
    float tot = red[0] + red[1] + red[2] + red[3];
    float scale = rsqrtf(tot * (1.f / DMODEL) + EPSV);
    size_t base = (size_t)row * DMODEL;
    x[base + t] = v0;
    x[base + t + 256] = v1;
    xn[base + t] = v0 * scale * w[t];
    xn[base + t + 256] = v1 * scale * w[t + 256];
}

// ---------------- rmsnorm (one block per row) ----------------
__global__ __launch_bounds__(256) void k_rmsnorm(const float* __restrict__ in,
                                                 const float* __restrict__ w,
                                                 float* __restrict__ out) {
    int row = blockIdx.x;
    const float* xr = in + (size_t)row * DMODEL;
    float s = 0.f;
    for (int d = threadIdx.x; d < DMODEL; d += 256) { float v = xr[d]; s += v * v; }
    __shared__ float red[4];
    int lane = threadIdx.x & 63, wv = threadIdx.x >> 6;
    for (int o = 32; o > 0; o >>= 1) s += __shfl_xor(s, o);
    if (lane == 0) red[wv] = s;
    __syncthreads();
    float tot = red[0] + red[1] + red[2] + red[3];
    float scale = rsqrtf(tot * (1.f / DMODEL) + EPSV);
    for (int d = threadIdx.x; d < DMODEL; d += 256)
        out[(size_t)row * DMODEL + d] = xr[d] * scale * w[d];
}

// ---------------- split-K matmul partial (64x64 tile + register prefetch) ------
__global__ __launch_bounds__(256) void k_mm_part(const float* __restrict__ A,
                                                 const float* __restrict__ W,
                                                 float* __restrict__ Cp,
                                                 int K, int N, int kc) {
    __shared__ float As[16][68];
    __shared__ float Ws[16][68];
    const int bn = blockIdx.x * 64;
    const int bm = blockIdx.y * 64;
    const int kz = blockIdx.z * kc;
    const int tx = threadIdx.x & 15;
    const int ty = threadIdx.x >> 4;
    float ar[4], wr[4];
#pragma unroll
    for (int r = 0; r < 4; ++r) {
        int idx = threadIdx.x + r * 256;
        int m = idx >> 4, kk = idx & 15;
        ar[r] = A[(size_t)(bm + m) * K + kz + kk];
        int n = idx & 63, kw = idx >> 6;
        wr[r] = W[(size_t)(kz + kw) * N + bn + n];
    }
    float acc[4][4] = {};
    for (int k0 = kz; k0 < kz + kc; k0 += 16) {
#pragma unroll
        for (int r = 0; r < 4; ++r) {
            int idx = threadIdx.x + r * 256;
            int m = idx >> 4, kk = idx & 15;
            As[kk][m] = ar[r];
            int n = idx & 63, kw = idx >> 6;
            Ws[kw][n] = wr[r];
        }
        __syncthreads();
        if (k0 + 16 < kz + kc) {   // prefetch next chunk into registers
#pragma unroll
            for (int r = 0; r < 4; ++r) {
                int idx = threadIdx.x + r * 256;
                int m = idx >> 4, kk = idx & 15;
                ar[r] = A[(size_t)(bm + m) * K + k0 + 16 + kk];
                int n = idx & 63, kw = idx >> 6;
                wr[r] = W[(size_t)(k0 + 16 + kw) * N + bn + n];
            }
        }
#pragma unroll
        for (int kk = 0; kk < 16; ++kk) {
            float4 av = *(const float4*)&As[kk][ty * 4];
            float4 bv = *(const float4*)&Ws[kk][tx * 4];
            float a[4] = {av.x, av.y, av.z, av.w};
            float b[4] = {bv.x, bv.y, bv.z, bv.w};
#pragma unroll
            for (int i = 0; i < 4; ++i)
#pragma unroll
                for (int j = 0; j < 4; ++j)
                    acc[i][j] = fmaf(a[i], b[j], acc[i][j]);
        }
        __syncthreads();
    }
    float* cp = Cp + (size_t)blockIdx.z * (size_t)(gridDim.y * 64) * N;
#pragma unroll
    for (int i = 0; i < 4; ++i) {
        int m = bm + ty * 4 + i;
#pragma unroll
        for (int j = 0; j < 4; ++j)
            cp[(size_t)m * N + bn + tx * 4 + j] = acc[i][j];
    }
}

// ---------------- gate+up combined split-K partial: 4 slices + prefetch --------
__global__ __launch_bounds__(256) void k_gu_part(const float* __restrict__ A,
                                                 const float* __restrict__ Wg,
                                                 const float* __restrict__ Wu,
                                                 float* __restrict__ GU) {
    __shared__ float As[16][68];
    __shared__ float Ws[16][68];
    const int bn = blockIdx.x * 64;
    const int bm = blockIdx.y * 64;
    const int z = blockIdx.z;
    const float* W = (z >> 1) ? Wu : Wg;
    const int kz = (z & 1) * 256;
    const int tx = threadIdx.x & 15;
    const int ty = threadIdx.x >> 4;
    float ar[4], wr[4];
#pragma unroll
    for (int r = 0; r < 4; ++r) {
        int idx = threadIdx.x + r * 256;
        int m = idx >> 4, kk = idx & 15;
        ar[r] = A[(size_t)(bm + m) * DMODEL + kz + kk];
        int n = idx & 63, kw = idx >> 6;
        wr[r] = W[(size_t)(kz + kw) * FF + bn + n];
    }
    float acc[4][4] = {};
    for (int k0 = kz; k0 < kz + 256; k0 += 16) {
#pragma unroll
        for (int r = 0; r < 4; ++r) {
            int idx = threadIdx.x + r * 256;
            int m = idx >> 4, kk = idx & 15;
            As[kk][m] = ar[r];
            int n = idx & 63, kw = idx >> 6;
            Ws[kw][n] = wr[r];
        }
        __syncthreads();
        if (k0 + 16 < kz + 256) {
#pragma unroll
            for (int r = 0; r < 4; ++r) {
                int idx = threadIdx.x + r * 256;
                int m = idx >> 4, kk = idx & 15;
                ar[r] = A[(size_t)(bm + m) * DMODEL + k0 + 16 + kk];
                int n = idx & 63, kw = idx >> 6;
                wr[r] = W[(size_t)(k0 + 16 + kw) * FF + bn + n];
            }
        }
#pragma unroll
        for (int kk = 0; kk < 16; ++kk) {
            float4 av = *(const float4*)&As[kk][ty * 4];
            float4 bv = *(const float4*)&Ws[kk][tx * 4];
            float a[4] = {av.x, av.y, av.z, av.w};
            float b[4] = {bv.x, bv.y, bv.z, bv.w};
#pragma unroll
            for (int i = 0; i < 4; ++i)
#pragma unroll
                for (int j = 0; j < 4; ++j)
                    acc[i][j] = fmaf(a[i], b[j], acc[i][j]);
        }
        __syncthreads();
    }
    float* cp = GU + (size_t)z * (NTOK * FF);
#pragma unroll
    for (int i = 0; i < 4; ++i) {
        int m = bm + ty * 4 + i;
#pragma unroll
        for (int j = 0; j < 4; ++j)
            cp[(size_t)m * FF + bn + tx * 4 + j] = acc[i][j];
    }
}

// ---------------- split-K elementwise reduce (+optional gelu) ----------------
__global__ void k_mm_finish(const float* __restrict__ Cp, const float* __restrict__ res,
                            float* __restrict__ C, int tot, int zstride, int nz, int act) {
    int i = blockIdx.x * 256 + threadIdx.x;
    if (i >= tot) return;
    float s = 0.f;
    for (int z = 0; z < nz; ++z) s += Cp[(size_t)z * zstride + i];
    if (res) s += res[i];
    if (act == 1) {  // gelu (tanh approx, jax default)
        float xg = s;
        float inner = 0.79788456080286536f * (xg + 0.044715f * xg * xg * xg);
        s = 0.5f * xg * (1.f + tanhf(inner));
    }
    C[i] = s;
}

// ---------------- reduce + silu(g)*u  (gate z=0..1, up z=2..3) ----------------
__global__ void k_finish_silumul(const float* __restrict__ GU, float* __restrict__ C) {
    int i = blockIdx.x * 256 + threadIdx.x;   // tot = 256*1536
    float g = GU[i] + GU[(size_t)(NTOK * FF) + i];
    float u = GU[(size_t)(2 * NTOK * FF) + i] + GU[(size_t)(3 * NTOK * FF) + i];
    float sig = 1.f / (1.f + expf(-g));
    C[i] = g * sig * u;
}

// ---------------- reduce + residual + dual write (raw, rmsnorm) ----------------
__global__ __launch_bounds__(256) void k_finish_norm(const float* __restrict__ Cp,
                                                     const float* __restrict__ res,
                                                     const float* __restrict__ normw,
                                                     float* __restrict__ out_raw,
                                                     float* __restrict__ out_norm,
                                                     int nz) {
    int row = blockIdx.x, t = threadIdx.x;
    int c0 = t, c1 = t + 256;
    size_t base = (size_t)row * DMODEL;
    float v0 = 0.f, v1 = 0.f;
    for (int z = 0; z < nz; ++z) {
        size_t zb = (size_t)z * (NTOK * DMODEL) + base;
        v0 += Cp[zb + c0];
        v1 += Cp[zb + c1];
    }
    v0 += res[base + c0];
    v1 += res[base + c1];
    float ss = v0 * v0 + v1 * v1;
    __shared__ float red[4];
    int lane = t & 63, wv = t >> 6;
    for (int o = 32; o > 0; o >>= 1) ss += __shfl_xor(ss, o);
    if (lane == 0) red[wv] = ss;
    __syncthreads();
    float tot = red[0] + red[1] + red[2] + red[3];
    float scale = rsqrtf(tot * (1.f / DMODEL) + EPSV);
    out_raw[base + c0] = v0;
    out_raw[base + c1] = v1;
    out_norm[base + c0] = v0 * scale * normw[c0];
    out_norm[base + c1] = v1 * scale * normw[c1];
}

// ---------------- qkv reduce + RoPE fused (z=4 slices, N=1536) ----------------
__global__ __launch_bounds__(256) void k_qkv_finish_rope(const float* __restrict__ Cp,
                                                         float* __restrict__ qkv) {
    int pos = blockIdx.x, t = threadIdx.x;
    int h = t >> 5, d = t & 31;
    size_t base = (size_t)pos * FF;
    auto S = [&](int col) {
        float s = 0.f;
#pragma unroll
        for (int z = 0; z < 4; ++z) s += Cp[(size_t)z * (NTOK * FF) + base + col];
        return s;
    };
    int cq0 = h * HD + d, cq1 = cq0 + HALF;
    int ck0 = DMODEL + cq0, ck1 = ck0 + HALF;
    int cv0 = 2 * DMODEL + t, cv1 = cv0 + 256;
    float q0 = S(cq0), q1 = S(cq1);
    float k0 = S(ck0), k1 = S(ck1);
    float v0 = S(cv0), v1 = S(cv1);
    float inv = powf(10000.f, -(float)d / 32.f);
    float ang = (float)pos * inv;
    float c = cosf(ang), s = sinf(ang);
    qkv[base + cq0] = q0 * c - q1 * s;
    qkv[base + cq1] = q0 * s + q1 * c;
    qkv[base + ck0] = k0 * c - k1 * s;
    qkv[base + ck1] = k0 * s + k1 * c;
    qkv[base + cv0] = v0;
    qkv[base + cv1] = v1;
}

// ---------------- attention: one block per (head, query) ----------------
__global__ __launch_bounds__(256) void k_attn(const float* __restrict__ qkv,
                                              float* __restrict__ out) {
    int h = blockIdx.x;
    int qi = blockIdx.y;
    int t = threadIdx.x;
    __shared__ float qs[HD];
    __shared__ float ps[NTOK];
    __shared__ float red[4];
    __shared__ float red2[4];
    __shared__ float os[4][HD];
    if (t < HD) qs[t] = qkv[(size_t)qi * FF + h * HD + t];
    __syncthreads();
    float sc = -1e30f;
    if (t <= qi) {
        const float* kr = qkv + (size_t)t * FF + DMODEL + h * HD;
        float s = 0.f;
        for (int d = 0; d < HD; ++d) s = fmaf(qs[d], kr[d], s);
        sc = s * 0.125f;
    }
    float m = sc;
    for (int o = 32; o > 0; o >>= 1) m = fmaxf(m, __shfl_xor(m, o));
    int lane = t & 63, wv = t >> 6;
    if (lane == 0) red[wv] = m;
    __syncthreads();
    m = fmaxf(fmaxf(red[0], red[1]), fmaxf(red[2], red[3]));
    float e = (t <= qi) ? expf(sc - m) : 0.f;
    ps[t] = e;
    float sum = e;
    for (int o = 32; o > 0; o >>= 1) sum += __shfl_xor(sum, o);
    if (lane == 0) red2[wv] = sum;
    __syncthreads();
    sum = red2[0] + red2[1] + red2[2] + red2[3];
    float inv = 1.f / sum;
    int d = t & 63, g = t >> 6;
    float acc = 0.f;
    for (int ki = g; ki <= qi; ki += 4)
        acc = fmaf(ps[ki], qkv[(size_t)ki * FF + 2 * DMODEL + h * HD + d], acc);
    os[g][d] = acc * inv;
    __syncthreads();
    if (t < HD)
        out[(size_t)qi * DMODEL + h * HD + t] = os[0][t] + os[1][t] + os[2][t] + os[3][t];
}

// ---------------- halt dots + ACT combine + A/B build, one block per token ----
__global__ __launch_bounds__(256) void k_haltactab(const float* __restrict__ H,
                                                   const float* __restrict__ wh,
                                                   const float* __restrict__ bptr,
                                                   float* __restrict__ ponder_out,
                                                   float* __restrict__ w_out,
                                                   __hip_bfloat16* __restrict__ A,
                                                   __hip_bfloat16* __restrict__ Bm) {
    int i = blockIdx.x, t = threadIdx.x;
    int lane = t & 63, wv = t >> 6;
    __shared__ float red[4];
    __shared__ float hvals[3];
    __shared__ float hw[4];
    for (int s = 1; s <= 3; ++s) {
        const float* hr = H + ((size_t)s * NTOK + i) * DMODEL;
        float a = hr[t] * wh[t] + hr[t + 256] * wh[t + 256];
        for (int o = 32; o > 0; o >>= 1) a += __shfl_xor(a, o);
        if (lane == 0) red[wv] = a;
        __syncthreads();
        if (t == 0)
            hvals[s - 1] = 1.f / (1.f + expf(-(red[0] + red[1] + red[2] + red[3] + bptr[0])));
        __syncthreads();
    }
    if (t == 0) {
        float p[4] = {0.f, hvals[0], hvals[1], hvals[2]};
        float cum = 0.f, rem = 0.f;
        int nrun = 0;
#pragma unroll
        for (int s = 0; s < 4; ++s) {
            float prev = cum;
            cum += p[s];
            bool running = prev < THR;
            bool use_rem = running && ((cum >= THR) || (s == 3));
            float v = 0.f;
            if (running) {
                v = use_rem ? (1.f - prev) : p[s];
                if (use_rem) rem += (1.f - prev);
                nrun++;
            }
            hw[s] = v;
            w_out[i * 4 + s] = v;
        }
        ponder_out[i] = (float)nrun + rem;
    }
    __syncthreads();
    float w0 = hw[0], w1 = hw[1], w2 = hw[2], w3 = hw[3];
    size_t base = (size_t)i * DMODEL;
#pragma unroll
    for (int r = 0; r < 2; ++r) {
        int d = t + r * 256;
        float h0 = H[base + d];
        float h1 = H[(size_t)(NTOK * DMODEL) + base + d];
        float h2 = H[(size_t)(2 * NTOK * DMODEL) + base + d];
        float h3 = H[(size_t)(3 * NTOK * DMODEL) + base + d];
        float h4 = H[(size_t)(4 * NTOK * DMODEL) + base + d];
        A[base + d]  = __float2bfloat16(w0 * h0 + w1 * h1 + w2 * h2 + w3 * h3);
        Bm[base + d] = __float2bfloat16(w0 * h1 + w1 * h2 + w2 * h3 + w3 * h4);
    }
}

// ---------------- final logits via 32x32x16 MFMA + 2-deep register prefetch ----
// R13 structure (proven numerics) with TWO register sets (even/odd tiles):
// tile t+2's global loads issue right after set(t&1) is stored to LDS, giving
// each load ~2 iterations (>900cy) to land — the per-iteration vmcnt stall that
// capped R13 at ~2TB/s disappears (counted-vmcnt via distinct register sets).
__global__ __launch_bounds__(512) void k_logits_mfma(const __hip_bfloat16* __restrict__ Abf,
                                                     const __hip_bfloat16* __restrict__ Bbf,
                                                     const float* __restrict__ Wy,
                                                     const float* __restrict__ Wd,
                                                     float* __restrict__ out) {
    __shared__ short Alds[256 * 40];   // [row][k] pad 40
    __shared__ short Blds[256 * 40];
    __shared__ short Wys[64 * 40];     // [col][k] pad 40
    __shared__ short Wds[64 * 40];
    const int tid  = threadIdx.x;
    const int wave = tid >> 6;
    const int lane = tid & 63;
    const int l31  = lane & 31;
    const int hi8  = (lane >> 5) * 8;
    const int wv_row = (wave & 3) * 64;
    const int wv_col = (wave >> 2) * 32;
    const int sr0 = tid >> 2;
    const int skp = (tid & 3) * 8;
    const int wc  = tid & 63;
    const int wk4 = (tid >> 6) * 4;

    f32x16 acc0 = {};
    f32x16 acc1 = {};

    const size_t woff = (size_t)wk4 * VOCAB + blockIdx.x * 64 + wc;
    const float* gy = Wy + woff;
    const float* gd = Wd + woff;

    float ry0[4], rd0[4], ry1[4], rd1[4];
    bf16x8 a00, a01, b00, b01, a10, a11, b10, b11;

    auto loadset = [&](int kt, float* ry, float* rd, bf16x8& A0, bf16x8& A1,
                       bf16x8& B0, bf16x8& B1) {
        const int kn = kt * 32;
        const float* gy2 = gy + (size_t)kn * VOCAB;
        const float* gd2 = gd + (size_t)kn * VOCAB;
#pragma unroll
        for (int j = 0; j < 4; ++j) {
            ry[j] = gy2[(size_t)j * VOCAB];
            rd[j] = gd2[(size_t)j * VOCAB];
        }
        A0 = *(const bf16x8*)(Abf + (size_t)sr0 * DMODEL + kn + skp);
        A1 = *(const bf16x8*)(Abf + (size_t)(sr0 + 128) * DMODEL + kn + skp);
        B0 = *(const bf16x8*)(Bbf + (size_t)sr0 * DMODEL + kn + skp);
        B1 = *(const bf16x8*)(Bbf + (size_t)(sr0 + 128) * DMODEL + kn + skp);
    };
    auto stage = [&](float* ry, float* rd, bf16x8& A0, bf16x8& A1,
                     bf16x8& B0, bf16x8& B1) {
        short4 sy, sd;
        sy.x = f2b(ry[0]); sy.y = f2b(ry[1]); sy.z = f2b(ry[2]); sy.w = f2b(ry[3]);
        sd.x = f2b(rd[0]); sd.y = f2b(rd[1]); sd.z = f2b(rd[2]); sd.w = f2b(rd[3]);
        *(short4*)&Wys[wc * 40 + wk4] = sy;
        *(short4*)&Wds[wc * 40 + wk4] = sd;
        *(bf16x8*)&Alds[sr0 * 40 + skp]         = A0;
        *(bf16x8*)&Alds[(sr0 + 128) * 40 + skp] = A1;
        *(bf16x8*)&Blds[sr0 * 40 + skp]         = B0;
        *(bf16x8*)&Blds[(sr0 + 128) * 40 + skp] = B1;
    };
    auto compute = [&]() {
#pragma unroll
        for (int h = 0; h < 2; ++h) {
            const int klo = h * 16 + hi8;
            const bf16x8 wyf = *(const bf16x8*)&Wys[(wv_col + l31) * 40 + klo];
            const bf16x8 wdf = *(const bf16x8*)&Wds[(wv_col + l31) * 40 + klo];
            const bf16x8 ay0 = *(const bf16x8*)&Alds[(wv_row + l31) * 40 + klo];
            const bf16x8 ay1 = *(const bf16x8*)&Alds[(wv_row + 32 + l31) * 40 + klo];
            const bf16x8 ad0 = *(const bf16x8*)&Blds[(wv_row + l31) * 40 + klo];
            const bf16x8 ad1 = *(const bf16x8*)&Blds[(wv_row + 32 + l31) * 40 + klo];
            acc0 = __builtin_amdgcn_mfma_f32_32x32x16_bf16(ay0, wyf, acc0, 0, 0, 0);
            acc0 = __builtin_amdgcn_mfma_f32_32x32x16_bf16(ad0, wdf, acc0, 0, 0, 0);
            acc1 = __builtin_amdgcn_mfma_f32_32x32x16_bf16(ay1, wyf, acc1, 0, 0, 0);
            acc1 = __builtin_amdgcn_mfma_f32_32x32x16_bf16(ad1, wdf, acc1, 0, 0, 0);
        }
    };

    loadset(0, ry0, rd0, a00, a01, b00, b01);
    loadset(1, ry1, rd1, a10, a11, b10, b11);

#pragma unroll 1
    for (int tt = 0; tt < 8; ++tt) {
        const int t0 = tt * 2;
        __syncthreads();                       // prev compute's LDS reads done
        stage(ry0, rd0, a00, a01, b00, b01);   // waits only on set0's loads
        if (t0 + 2 < 16) loadset(t0 + 2, ry0, rd0, a00, a01, b00, b01);
        __syncthreads();                       // tile t0 visible
        compute();
        __syncthreads();
        stage(ry1, rd1, a10, a11, b10, b11);   // waits only on set1's loads
        if (t0 + 3 < 16) loadset(t0 + 3, ry1, rd1, a10, a11, b10, b11);
        __syncthreads();                       // tile t0+1 visible
        compute();
    }
    // C/D layout (verified): col = lane&31, row = (reg&3) + 8*(reg>>2) + 4*(lane>>5)
    const int col = blockIdx.x * 64 + wv_col + l31;
    const int rbase = (lane >> 5) * 4;
#pragma unroll
    for (int reg = 0; reg < 16; ++reg) {
        int rowin = (reg & 3) + 8 * (reg >> 2) + rbase;
        out[(size_t)(wv_row + rowin) * VOCAB + col] = acc0[reg];
        out[(size_t)(wv_row + 32 + rowin) * VOCAB + col] = acc1[reg];
    }
}

extern "C" void kernel_launch(void* const* d_in, const int* in_sizes, int n_in,
                              void* d_out, int out_size, void* d_ws, size_t ws_size,
                              hipStream_t stream) {
    const int*   ids          = (const int*)d_in[0];
    const float* emb          = (const float*)d_in[1];
    const float* attn_norm_w  = (const float*)d_in[2];
    const float* mlp_norm_w   = (const float*)d_in[3];
    const float* wqkv         = (const float*)d_in[4];
    const float* wo           = (const float*)d_in[5];
    const float* w_gate       = (const float*)d_in[6];
    const float* w_up         = (const float*)d_in[7];
    const float* w_down       = (const float*)d_in[8];
    const float* final_norm_w = (const float*)d_in[9];
    const float* rc_norm_w    = (const float*)d_in[10];
    const float* rc_w1        = (const float*)d_in[11];
    const float* rc_w2        = (const float*)d_in[12];
    const float* w_y          = (const float*)d_in[13];
    const float* w_delta      = (const float*)d_in[14];
    const float* w_halt       = (const float*)d_in[15];
    const float* b_halt       = (const float*)d_in[16];
    float* out = (float*)d_out;

    float* ws = (float*)d_ws;
    // Live-range map (floats) — identical to rounds 10-13 (proven):
    //   x 0.. | xn 131072.. | qkv 262144.. | attnout 655360.. | g 786432..
    //   t1 1179648.. | states 1703936.. | states2 1835008.. | H 1966080..
    //   Abf 2623488.. | Bbf 2754560.. | Cp 2885632.. | GU 1179648.. (backbone only)
    float* x       = ws + 0;
    float* xn      = ws + 131072;
    float* qkv     = ws + 262144;
    float* attnout = ws + 655360;
    float* g       = ws + 786432;
    float* t1      = ws + 1179648;
    float* states  = ws + 1703936;
    float* states2 = ws + 1835008;
    float* H       = ws + 1966080;
    __hip_bfloat16* Abf = (__hip_bfloat16*)(ws + 2623488);
    __hip_bfloat16* Bbf = (__hip_bfloat16*)(ws + 2754560);
    float* Cp      = ws + 2885632;
    float* GU      = ws + 1179648;

    // ---------- backbone ----------
    k_embed_norm<<<NTOK, 256, 0, stream>>>(ids, emb, attn_norm_w, x, xn);
    for (int l = 0; l < NLAYER; ++l) {
        k_mm_part<<<dim3(FF / 64, 4, 4), 256, 0, stream>>>(
            xn, wqkv + (size_t)l * DMODEL * FF, Cp, DMODEL, FF, 128);
        k_qkv_finish_rope<<<NTOK, 256, 0, stream>>>(Cp, qkv);
        k_attn<<<dim3(NHEAD, NTOK), 256, 0, stream>>>(qkv, attnout);
        k_mm_part<<<dim3(DMODEL / 64, 4, 8), 256, 0, stream>>>(
            attnout, wo + (size_t)l * DMODEL * DMODEL, Cp, DMODEL, DMODEL, 64);
        k_finish_norm<<<NTOK, 256, 0, stream>>>(Cp, x, mlp_norm_w + l * DMODEL, x, xn, 8);
        k_gu_part<<<dim3(FF / 64, 4, 4), 256, 0, stream>>>(
            xn, w_gate + (size_t)l * DMODEL * FF, w_up + (size_t)l * DMODEL * FF, GU);
        k_finish_silumul<<<NTOK * FF / 256, 256, 0, stream>>>(GU, g);
        k_mm_part<<<dim3(DMODEL / 64, 4, 12), 256, 0, stream>>>(
            g, w_down + (size_t)l * FF * DMODEL, Cp, FF, DMODEL, 128);
        const float* nw = (l == 0) ? (attn_norm_w + DMODEL) : final_norm_w;
        float* nout = (l == 0) ? xn : states;
        k_finish_norm<<<NTOK, 256, 0, stream>>>(Cp, x, nw, x, nout, 12);
    }

    // ---------- refinement steps (halt path stays f32) ----------
    k_rmsnorm<<<NTOK, 256, 0, stream>>>(states, rc_norm_w, H);
    float* scur = states;
    float* snxt = states2;
    for (int s = 0; s < NSTEPS; ++s) {
        k_mm_part<<<dim3(RCFF / 64, 4, 4), 256, 0, stream>>>(
            H + (size_t)s * NTOK * DMODEL, rc_w1, Cp, DMODEL, RCFF, 128);
        k_mm_finish<<<NTOK * RCFF / 256, 256, 0, stream>>>(
            Cp, nullptr, t1, NTOK * RCFF, NTOK * RCFF, 4, 1);
        k_mm_part<<<dim3(DMODEL / 64, 4, 16), 256, 0, stream>>>(
            t1, rc_w2, Cp, RCFF, DMODEL, 128);
        k_finish_norm<<<NTOK, 256, 0, stream>>>(
            Cp, scur, rc_norm_w, snxt, H + (size_t)(s + 1) * NTOK * DMODEL, 16);
        float* tmp = scur; scur = snxt; snxt = tmp;
    }

    // ---------- halt + ACT + A/B in one kernel ----------
    k_haltactab<<<NTOK, 256, 0, stream>>>(H, w_halt, b_halt,
                                          out + (size_t)NTOK * VOCAB,
                                          out + (size_t)NTOK * VOCAB + NTOK,
                                          Abf, Bbf);

    // ---------- final logits (MFMA 32x32x16 bf16, 2-deep prefetch) ----------
    k_logits_mfma<<<VOCAB / 64, 512, 0, stream>>>(Abf, Bbf, w_y, w_delta, out);
}

// Round 16
// 369.951 us; speedup vs baseline: 1.0781x; 1.0135x over previous
//
#include <hip/hip_runtime.h>
#include <hip/hip_bf16.h>

#define NTOK   256
#define DMODEL 512
#define NHEAD  8
#define HD     64
#define HALF   32
#define FF     1536
#define RCFF   2048
#define VOCAB  32000
#define NLAYER 2
#define NSTEPS 4
#define EPSV   1e-6f
#define THR    0.99f

typedef __attribute__((ext_vector_type(8))) short bf16x8;
typedef __attribute__((ext_vector_type(4))) float f32x4;
typedef __attribute__((ext_vector_type(16))) float f32x16;

__device__ __forceinline__ short f2b(float x) {
    return (short)__hip_bfloat16_raw(__float2bfloat16(x)).x;
}

// ---------------- embedding gather + first rmsnorm fused ----------------
__global__ __launch_bounds__(256) void k_embed_norm(const int* __restrict__ ids,
                                                    const float* __restrict__ emb,
                                                    const float* __restrict__ w,
                                                    float* __restrict__ x,
                                                    float* __restrict__ xn) {
    int row = blockIdx.x, t = threadIdx.x;
    int id = ids[row];
    const float* er = emb + (size_t)id * DMODEL;
    float v0 = er[t], v1 = er[t + 256];
    float ss = v0 * v0 + v1 * v1;
    __shared__ float red[4];
    int lane = t & 63, wv = t >> 6;
    for (int o = 32; o > 0; o >>= 1) ss += __shfl_xor(ss, o);
    if (lane == 0) red[wv] = ss;
    __syncthreads();
    float tot = red[0] + red[1] + red[2] + red[3];
    float scale = rsqrtf(tot * (1.f / DMODEL) + EPSV);
    size_t base = (size_t)row * DMODEL;
    x[base + t] = v0;
    x[base + t + 256] = v1;
    xn[base + t] = v0 * scale * w[t];
    xn[base + t + 256] = v1 * scale * w[t + 256];
}

// ---------------- split-K matmul partial (64x64 tile + register prefetch) ------
__global__ __launch_bounds__(256) void k_mm_part(const float* __restrict__ A,
                                                 const float* __restrict__ W,
                                                 float* __restrict__ Cp,
                                                 int K, int N, int kc) {
    __shared__ float As[16][68];
    __shared__ float Ws[16][68];
    const int bn = blockIdx.x * 64;
    const int bm = blockIdx.y * 64;
    const int kz = blockIdx.z * kc;
    const int tx = threadIdx.x & 15;
    const int ty = threadIdx.x >> 4;
    float ar[4], wr[4];
#pragma unroll
    for (int r = 0; r < 4; ++r) {
        int idx = threadIdx.x + r * 256;
        int m = idx >> 4, kk = idx & 15;
        ar[r] = A[(size_t)(bm + m) * K + kz + kk];
        int n = idx & 63, kw = idx >> 6;
        wr[r] = W[(size_t)(kz + kw) * N + bn + n];
    }
    float acc[4][4] = {};
    for (int k0 = kz; k0 < kz + kc; k0 += 16) {
#pragma unroll
        for (int r = 0; r < 4; ++r) {
            int idx = threadIdx.x + r * 256;
            int m = idx >> 4, kk = idx & 15;
            As[kk][m] = ar[r];
            int n = idx & 63, kw = idx >> 6;
            Ws[kw][n] = wr[r];
        }
        __syncthreads();
        if (k0 + 16 < kz + kc) {   // prefetch next chunk into registers
#pragma unroll
            for (int r = 0; r < 4; ++r) {
                int idx = threadIdx.x + r * 256;
                int m = idx >> 4, kk = idx & 15;
                ar[r] = A[(size_t)(bm + m) * K + k0 + 16 + kk];
                int n = idx & 63, kw = idx >> 6;
                wr[r] = W[(size_t)(k0 + 16 + kw) * N + bn + n];
            }
        }
#pragma unroll
        for (int kk = 0; kk < 16; ++kk) {
            float4 av = *(const float4*)&As[kk][ty * 4];
            float4 bv = *(const float4*)&Ws[kk][tx * 4];
            float a[4] = {av.x, av.y, av.z, av.w};
            float b[4] = {bv.x, bv.y, bv.z, bv.w};
#pragma unroll
            for (int i = 0; i < 4; ++i)
#pragma unroll
                for (int j = 0; j < 4; ++j)
                    acc[i][j] = fmaf(a[i], b[j], acc[i][j]);
        }
        __syncthreads();
    }
    float* cp = Cp + (size_t)blockIdx.z * (size_t)(gridDim.y * 64) * N;
#pragma unroll
    for (int i = 0; i < 4; ++i) {
        int m = bm + ty * 4 + i;
#pragma unroll
        for (int j = 0; j < 4; ++j)
            cp[(size_t)m * N + bn + tx * 4 + j] = acc[i][j];
    }
}

// ---------------- gate+up combined split-K partial: 4 slices + prefetch --------
__global__ __launch_bounds__(256) void k_gu_part(const float* __restrict__ A,
                                                 const float* __restrict__ Wg,
                                                 const float* __restrict__ Wu,
                                                 float* __restrict__ GU) {
    __shared__ float As[16][68];
    __shared__ float Ws[16][68];
    const int bn = blockIdx.x * 64;
    const int bm = blockIdx.y * 64;
    const int z = blockIdx.z;
    const float* W = (z >> 1) ? Wu : Wg;
    const int kz = (z & 1) * 256;
    const int tx = threadIdx.x & 15;
    const int ty = threadIdx.x >> 4;
    float ar[4], wr[4];
#pragma unroll
    for (int r = 0; r < 4; ++r) {
        int idx = threadIdx.x + r * 256;
        int m = idx >> 4, kk = idx & 15;
        ar[r] = A[(size_t)(bm + m) * DMODEL + kz + kk];
        int n = idx & 63, kw = idx >> 6;
        wr[r] = W[(size_t)(kz + kw) * FF + bn + n];
    }
    float acc[4][4] = {};
    for (int k0 = kz; k0 < kz + 256; k0 += 16) {
#pragma unroll
        for (int r = 0; r < 4; ++r) {
            int idx = threadIdx.x + r * 256;
            int m = idx >> 4, kk = idx & 15;
            As[kk][m] = ar[r];
            int n = idx & 63, kw = idx >> 6;
            Ws[kw][n] = wr[r];
        }
        __syncthreads();
        if (k0 + 16 < kz + 256) {
#pragma unroll
            for (int r = 0; r < 4; ++r) {
                int idx = threadIdx.x + r * 256;
                int m = idx >> 4, kk = idx & 15;
                ar[r] = A[(size_t)(bm + m) * DMODEL + k0 + 16 + kk];
                int n = idx & 63, kw = idx >> 6;
                wr[r] = W[(size_t)(k0 + 16 + kw) * FF + bn + n];
            }
        }
#pragma unroll
        for (int kk = 0; kk < 16; ++kk) {
            float4 av = *(const float4*)&As[kk][ty * 4];
            float4 bv = *(const float4*)&Ws[kk][tx * 4];
            float a[4] = {av.x, av.y, av.z, av.w};
            float b[4] = {bv.x, bv.y, bv.z, bv.w};
#pragma unroll
            for (int i = 0; i < 4; ++i)
#pragma unroll
                for (int j = 0; j < 4; ++j)
                    acc[i][j] = fmaf(a[i], b[j], acc[i][j]);
        }
        __syncthreads();
    }
    float* cp = GU + (size_t)z * (NTOK * FF);
#pragma unroll
    for (int i = 0; i < 4; ++i) {
        int m = bm + ty * 4 + i;
#pragma unroll
        for (int j = 0; j < 4; ++j)
            cp[(size_t)m * FF + bn + tx * 4 + j] = acc[i][j];
    }
}

// ---------------- split-K elementwise reduce (+optional gelu) ----------------
__global__ void k_mm_finish(const float* __restrict__ Cp, const float* __restrict__ res,
                            float* __restrict__ C, int tot, int zstride, int nz, int act) {
    int i = blockIdx.x * 256 + threadIdx.x;
    if (i >= tot) return;
    float s = 0.f;
    for (int z = 0; z < nz; ++z) s += Cp[(size_t)z * zstride + i];
    if (res) s += res[i];
    if (act == 1) {  // gelu (tanh approx, jax default)
        float xg = s;
        float inner = 0.79788456080286536f * (xg + 0.044715f * xg * xg * xg);
        s = 0.5f * xg * (1.f + tanhf(inner));
    }
    C[i] = s;
}

// ---------------- reduce + silu(g)*u  (gate z=0..1, up z=2..3) ----------------
__global__ void k_finish_silumul(const float* __restrict__ GU, float* __restrict__ C) {
    int i = blockIdx.x * 256 + threadIdx.x;   // tot = 256*1536
    float g = GU[i] + GU[(size_t)(NTOK * FF) + i];
    float u = GU[(size_t)(2 * NTOK * FF) + i] + GU[(size_t)(3 * NTOK * FF) + i];
    float sig = 1.f / (1.f + expf(-g));
    C[i] = g * sig * u;
}

// ---------------- reduce + residual + dual write (raw, rmsnorm) ----------------
__global__ __launch_bounds__(256) void k_finish_norm(const float* __restrict__ Cp,
                                                     const float* __restrict__ res,
                                                     const float* __restrict__ normw,
                                                     float* __restrict__ out_raw,
                                                     float* __restrict__ out_norm,
                                                     int nz) {
    int row = blockIdx.x, t = threadIdx.x;
    int c0 = t, c1 = t + 256;
    size_t base = (size_t)row * DMODEL;
    float v0 = 0.f, v1 = 0.f;
    for (int z = 0; z < nz; ++z) {
        size_t zb = (size_t)z * (NTOK * DMODEL) + base;
        v0 += Cp[zb + c0];
        v1 += Cp[zb + c1];
    }
    v0 += res[base + c0];
    v1 += res[base + c1];
    float ss = v0 * v0 + v1 * v1;
    __shared__ float red[4];
    int lane = t & 63, wv = t >> 6;
    for (int o = 32; o > 0; o >>= 1) ss += __shfl_xor(ss, o);
    if (lane == 0) red[wv] = ss;
    __syncthreads();
    float tot = red[0] + red[1] + red[2] + red[3];
    float scale = rsqrtf(tot * (1.f / DMODEL) + EPSV);
    out_raw[base + c0] = v0;
    out_raw[base + c1] = v1;
    out_norm[base + c0] = v0 * scale * normw[c0];
    out_norm[base + c1] = v1 * scale * normw[c1];
}

// -------- reduce + residual + raw + norm1 + CHAINED norm2(norm1) write --------
// For the backbone end: states = rmsnorm(x_final, final_norm_w), then
// H0 = rmsnorm(states, rc_norm_w). Second reduce runs on the normed vector.
__global__ __launch_bounds__(256) void k_finish_norm2(const float* __restrict__ Cp,
                                                      const float* __restrict__ res,
                                                      const float* __restrict__ normw,
                                                      const float* __restrict__ normw2,
                                                      float* __restrict__ out_raw,
                                                      float* __restrict__ out_norm,
                                                      float* __restrict__ out_norm2,
                                                      int nz) {
    int row = blockIdx.x, t = threadIdx.x;
    int c0 = t, c1 = t + 256;
    size_t base = (size_t)row * DMODEL;
    float v0 = 0.f, v1 = 0.f;
    for (int z = 0; z < nz; ++z) {
        size_t zb = (size_t)z * (NTOK * DMODEL) + base;
        v0 += Cp[zb + c0];
        v1 += Cp[zb + c1];
    }
    v0 += res[base + c0];
    v1 += res[base + c1];
    float ss = v0 * v0 + v1 * v1;
    __shared__ float red[4];
    int lane = t & 63, wv = t >> 6;
    for (int o = 32; o > 0; o >>= 1) ss += __shfl_xor(ss, o);
    if (lane == 0) red[wv] = ss;
    __syncthreads();
    float tot = red[0] + red[1] + red[2] + red[3];
    float scale = rsqrtf(tot * (1.f / DMODEL) + EPSV);
    float s0 = v0 * scale * normw[c0];
    float s1 = v1 * scale * normw[c1];
    out_raw[base + c0] = v0;
    out_raw[base + c1] = v1;
    out_norm[base + c0] = s0;
    out_norm[base + c1] = s1;
    // chained second rmsnorm on (s0,s1)
    float ss2 = s0 * s0 + s1 * s1;
    for (int o = 32; o > 0; o >>= 1) ss2 += __shfl_xor(ss2, o);
    __syncthreads();
    if (lane == 0) red[wv] = ss2;
    __syncthreads();
    float tot2 = red[0] + red[1] + red[2] + red[3];
    float scale2 = rsqrtf(tot2 * (1.f / DMODEL) + EPSV);
    out_norm2[base + c0] = s0 * scale2 * normw2[c0];
    out_norm2[base + c1] = s1 * scale2 * normw2[c1];
}

// ---------------- qkv reduce + RoPE fused (z=4 slices, N=1536) ----------------
__global__ __launch_bounds__(256) void k_qkv_finish_rope(const float* __restrict__ Cp,
                                                         float* __restrict__ qkv) {
    int pos = blockIdx.x, t = threadIdx.x;
    int h = t >> 5, d = t & 31;
    size_t base = (size_t)pos * FF;
    auto S = [&](int col) {
        float s = 0.f;
#pragma unroll
        for (int z = 0; z < 4; ++z) s += Cp[(size_t)z * (NTOK * FF) + base + col];
        return s;
    };
    int cq0 = h * HD + d, cq1 = cq0 + HALF;
    int ck0 = DMODEL + cq0, ck1 = ck0 + HALF;
    int cv0 = 2 * DMODEL + t, cv1 = cv0 + 256;
    float q0 = S(cq0), q1 = S(cq1);
    float k0 = S(ck0), k1 = S(ck1);
    float v0 = S(cv0), v1 = S(cv1);
    float inv = powf(10000.f, -(float)d / 32.f);
    float ang = (float)pos * inv;
    float c = cosf(ang), s = sinf(ang);
    qkv[base + cq0] = q0 * c - q1 * s;
    qkv[base + cq1] = q0 * s + q1 * c;
    qkv[base + ck0] = k0 * c - k1 * s;
    qkv[base + ck1] = k0 * s + k1 * c;
    qkv[base + cv0] = v0;
    qkv[base + cv1] = v1;
}

// ---------------- attention: one block per (head, query) ----------------
__global__ __launch_bounds__(256) void k_attn(const float* __restrict__ qkv,
                                              float* __restrict__ out) {
    int h = blockIdx.x;
    int qi = blockIdx.y;
    int t = threadIdx.x;
    __shared__ float qs[HD];
    __shared__ float ps[NTOK];
    __shared__ float red[4];
    __shared__ float red2[4];
    __shared__ float os[4][HD];
    if (t < HD) qs[t] = qkv[(size_t)qi * FF + h * HD + t];
    __syncthreads();
    float sc = -1e30f;
    if (t <= qi) {
        const float* kr = qkv + (size_t)t * FF + DMODEL + h * HD;
        float s = 0.f;
        for (int d = 0; d < HD; ++d) s = fmaf(qs[d], kr[d], s);
        sc = s * 0.125f;
    }
    float m = sc;
    for (int o = 32; o > 0; o >>= 1) m = fmaxf(m, __shfl_xor(m, o));
    int lane = t & 63, wv = t >> 6;
    if (lane == 0) red[wv] = m;
    __syncthreads();
    m = fmaxf(fmaxf(red[0], red[1]), fmaxf(red[2], red[3]));
    float e = (t <= qi) ? expf(sc - m) : 0.f;
    ps[t] = e;
    float sum = e;
    for (int o = 32; o > 0; o >>= 1) sum += __shfl_xor(sum, o);
    if (lane == 0) red2[wv] = sum;
    __syncthreads();
    sum = red2[0] + red2[1] + red2[2] + red2[3];
    float inv = 1.f / sum;
    int d = t & 63, g = t >> 6;
    float acc = 0.f;
    for (int ki = g; ki <= qi; ki += 4)
        acc = fmaf(ps[ki], qkv[(size_t)ki * FF + 2 * DMODEL + h * HD + d], acc);
    os[g][d] = acc * inv;
    __syncthreads();
    if (t < HD)
        out[(size_t)qi * DMODEL + h * HD + t] = os[0][t] + os[1][t] + os[2][t] + os[3][t];
}

// ---------------- halt dots + ACT combine + A/B build, one block per token ----
__global__ __launch_bounds__(256) void k_haltactab(const float* __restrict__ H,
                                                   const float* __restrict__ wh,
                                                   const float* __restrict__ bptr,
                                                   float* __restrict__ ponder_out,
                                                   float* __restrict__ w_out,
                                                   __hip_bfloat16* __restrict__ A,
                                                   __hip_bfloat16* __restrict__ Bm) {
    int i = blockIdx.x, t = threadIdx.x;
    int lane = t & 63, wv = t >> 6;
    __shared__ float red[4];
    __shared__ float hvals[3];
    __shared__ float hw[4];
    for (int s = 1; s <= 3; ++s) {
        const float* hr = H + ((size_t)s * NTOK + i) * DMODEL;
        float a = hr[t] * wh[t] + hr[t + 256] * wh[t + 256];
        for (int o = 32; o > 0; o >>= 1) a += __shfl_xor(a, o);
        if (lane == 0) red[wv] = a;
        __syncthreads();
        if (t == 0)
            hvals[s - 1] = 1.f / (1.f + expf(-(red[0] + red[1] + red[2] + red[3] + bptr[0])));
        __syncthreads();
    }
    if (t == 0) {
        float p[4] = {0.f, hvals[0], hvals[1], hvals[2]};
        float cum = 0.f, rem = 0.f;
        int nrun = 0;
#pragma unroll
        for (int s = 0; s < 4; ++s) {
            float prev = cum;
            cum += p[s];
            bool running = prev < THR;
            bool use_rem = running && ((cum >= THR) || (s == 3));
            float v = 0.f;
            if (running) {
                v = use_rem ? (1.f - prev) : p[s];
                if (use_rem) rem += (1.f - prev);
                nrun++;
            }
            hw[s] = v;
            w_out[i * 4 + s] = v;
        }
        ponder_out[i] = (float)nrun + rem;
    }
    __syncthreads();
    float w0 = hw[0], w1 = hw[1], w2 = hw[2], w3 = hw[3];
    size_t base = (size_t)i * DMODEL;
#pragma unroll
    for (int r = 0; r < 2; ++r) {
        int d = t + r * 256;
        float h0 = H[base + d];
        float h1 = H[(size_t)(NTOK * DMODEL) + base + d];
        float h2 = H[(size_t)(2 * NTOK * DMODEL) + base + d];
        float h3 = H[(size_t)(3 * NTOK * DMODEL) + base + d];
        float h4 = H[(size_t)(4 * NTOK * DMODEL) + base + d];
        A[base + d]  = __float2bfloat16(w0 * h0 + w1 * h1 + w2 * h2 + w3 * h3);
        Bm[base + d] = __float2bfloat16(w0 * h1 + w1 * h2 + w2 * h3 + w3 * h4);
    }
}

// ---------------- final logits via 32x32x16 MFMA (R13-exact, best) ----------
__global__ __launch_bounds__(512) void k_logits_mfma(const __hip_bfloat16* __restrict__ Abf,
                                                     const __hip_bfloat16* __restrict__ Bbf,
                                                     const float* __restrict__ Wy,
                                                     const float* __restrict__ Wd,
                                                     float* __restrict__ out) {
    __shared__ short Alds[256 * 40];   // [row][k] pad 40
    __shared__ short Blds[256 * 40];
    __shared__ short Wys[64 * 40];     // [col][k] pad 40
    __shared__ short Wds[64 * 40];
    const int tid  = threadIdx.x;
    const int wave = tid >> 6;
    const int lane = tid & 63;
    const int l31  = lane & 31;
    const int hi8  = (lane >> 5) * 8;
    const int wv_row = (wave & 3) * 64;
    const int wv_col = (wave >> 2) * 32;
    const int sr0 = tid >> 2;
    const int skp = (tid & 3) * 8;
    const int wc  = tid & 63;
    const int wk4 = (tid >> 6) * 4;

    f32x16 acc0 = {};
    f32x16 acc1 = {};

    const size_t woff = (size_t)wk4 * VOCAB + blockIdx.x * 64 + wc;
    const float* gy = Wy + woff;
    const float* gd = Wd + woff;

    float rys[4], rds[4];
#pragma unroll
    for (int j = 0; j < 4; ++j) {
        rys[j] = gy[(size_t)j * VOCAB];
        rds[j] = gd[(size_t)j * VOCAB];
    }
    bf16x8 ra0 = *(const bf16x8*)(Abf + (size_t)sr0 * DMODEL + skp);
    bf16x8 ra1 = *(const bf16x8*)(Abf + (size_t)(sr0 + 128) * DMODEL + skp);
    bf16x8 rb0 = *(const bf16x8*)(Bbf + (size_t)sr0 * DMODEL + skp);
    bf16x8 rb1 = *(const bf16x8*)(Bbf + (size_t)(sr0 + 128) * DMODEL + skp);

    for (int t = 0; t < 16; ++t) {
        __syncthreads();
        {
            short4 sy, sd;
            sy.x = f2b(rys[0]); sy.y = f2b(rys[1]); sy.z = f2b(rys[2]); sy.w = f2b(rys[3]);
            sd.x = f2b(rds[0]); sd.y = f2b(rds[1]); sd.z = f2b(rds[2]); sd.w = f2b(rds[3]);
            *(short4*)&Wys[wc * 40 + wk4] = sy;
            *(short4*)&Wds[wc * 40 + wk4] = sd;
            *(bf16x8*)&Alds[sr0 * 40 + skp]         = ra0;
            *(bf16x8*)&Alds[(sr0 + 128) * 40 + skp] = ra1;
            *(bf16x8*)&Blds[sr0 * 40 + skp]         = rb0;
            *(bf16x8*)&Blds[(sr0 + 128) * 40 + skp] = rb1;
        }
        if (t < 15) {
            const int kn = (t + 1) * 32;
            const float* gy2 = gy + (size_t)kn * VOCAB;
            const float* gd2 = gd + (size_t)kn * VOCAB;
#pragma unroll
            for (int j = 0; j < 4; ++j) {
                rys[j] = gy2[(size_t)j * VOCAB];
                rds[j] = gd2[(size_t)j * VOCAB];
            }
            ra0 = *(const bf16x8*)(Abf + (size_t)sr0 * DMODEL + kn + skp);
            ra1 = *(const bf16x8*)(Abf + (size_t)(sr0 + 128) * DMODEL + kn + skp);
            rb0 = *(const bf16x8*)(Bbf + (size_t)sr0 * DMODEL + kn + skp);
            rb1 = *(const bf16x8*)(Bbf + (size_t)(sr0 + 128) * DMODEL + kn + skp);
        }
        __syncthreads();
#pragma unroll
        for (int h = 0; h < 2; ++h) {
            const int klo = h * 16 + hi8;
            const bf16x8 wyf = *(const bf16x8*)&Wys[(wv_col + l31) * 40 + klo];
            const bf16x8 wdf = *(const bf16x8*)&Wds[(wv_col + l31) * 40 + klo];
            const bf16x8 ay0 = *(const bf16x8*)&Alds[(wv_row + l31) * 40 + klo];
            const bf16x8 ay1 = *(const bf16x8*)&Alds[(wv_row + 32 + l31) * 40 + klo];
            const bf16x8 ad0 = *(const bf16x8*)&Blds[(wv_row + l31) * 40 + klo];
            const bf16x8 ad1 = *(const bf16x8*)&Blds[(wv_row + 32 + l31) * 40 + klo];
            acc0 = __builtin_amdgcn_mfma_f32_32x32x16_bf16(ay0, wyf, acc0, 0, 0, 0);
            acc0 = __builtin_amdgcn_mfma_f32_32x32x16_bf16(ad0, wdf, acc0, 0, 0, 0);
            acc1 = __builtin_amdgcn_mfma_f32_32x32x16_bf16(ay1, wyf, acc1, 0, 0, 0);
            acc1 = __builtin_amdgcn_mfma_f32_32x32x16_bf16(ad1, wdf, acc1, 0, 0, 0);
        }
    }
    // C/D layout (verified): col = lane&31, row = (reg&3) + 8*(reg>>2) + 4*(lane>>5)
    const int col = blockIdx.x * 64 + wv_col + l31;
    const int rbase = (lane >> 5) * 4;
#pragma unroll
    for (int reg = 0; reg < 16; ++reg) {
        int rowin = (reg & 3) + 8 * (reg >> 2) + rbase;
        out[(size_t)(wv_row + rowin) * VOCAB + col] = acc0[reg];
        out[(size_t)(wv_row + 32 + rowin) * VOCAB + col] = acc1[reg];
    }
}

extern "C" void kernel_launch(void* const* d_in, const int* in_sizes, int n_in,
                              void* d_out, int out_size, void* d_ws, size_t ws_size,
                              hipStream_t stream) {
    const int*   ids          = (const int*)d_in[0];
    const float* emb          = (const float*)d_in[1];
    const float* attn_norm_w  = (const float*)d_in[2];
    const float* mlp_norm_w   = (const float*)d_in[3];
    const float* wqkv         = (const float*)d_in[4];
    const float* wo           = (const float*)d_in[5];
    const float* w_gate       = (const float*)d_in[6];
    const float* w_up         = (const float*)d_in[7];
    const float* w_down       = (const float*)d_in[8];
    const float* final_norm_w = (const float*)d_in[9];
    const float* rc_norm_w    = (const float*)d_in[10];
    const float* rc_w1        = (const float*)d_in[11];
    const float* rc_w2        = (const float*)d_in[12];
    const float* w_y          = (const float*)d_in[13];
    const float* w_delta      = (const float*)d_in[14];
    const float* w_halt       = (const float*)d_in[15];
    const float* b_halt       = (const float*)d_in[16];
    float* out = (float*)d_out;

    float* ws = (float*)d_ws;
    // Live-range map (floats) — identical to rounds 10-13 (proven):
    //   x 0.. | xn 131072.. | qkv 262144.. | attnout 655360.. | g 786432..
    //   t1 1179648.. | states 1703936.. | states2 1835008.. | H 1966080..
    //   Abf 2623488.. | Bbf 2754560.. | Cp 2885632.. | GU 1179648.. (backbone only)
    float* x       = ws + 0;
    float* xn      = ws + 131072;
    float* qkv     = ws + 262144;
    float* attnout = ws + 655360;
    float* g       = ws + 786432;
    float* t1      = ws + 1179648;
    float* states  = ws + 1703936;
    float* states2 = ws + 1835008;
    float* H       = ws + 1966080;
    __hip_bfloat16* Abf = (__hip_bfloat16*)(ws + 2623488);
    __hip_bfloat16* Bbf = (__hip_bfloat16*)(ws + 2754560);
    float* Cp      = ws + 2885632;
    float* GU      = ws + 1179648;

    // ---------- backbone ----------
    k_embed_norm<<<NTOK, 256, 0, stream>>>(ids, emb, attn_norm_w, x, xn);
    for (int l = 0; l < NLAYER; ++l) {
        k_mm_part<<<dim3(FF / 64, 4, 4), 256, 0, stream>>>(
            xn, wqkv + (size_t)l * DMODEL * FF, Cp, DMODEL, FF, 128);
        k_qkv_finish_rope<<<NTOK, 256, 0, stream>>>(Cp, qkv);
        k_attn<<<dim3(NHEAD, NTOK), 256, 0, stream>>>(qkv, attnout);
        k_mm_part<<<dim3(DMODEL / 64, 4, 8), 256, 0, stream>>>(
            attnout, wo + (size_t)l * DMODEL * DMODEL, Cp, DMODEL, DMODEL, 64);
        k_finish_norm<<<NTOK, 256, 0, stream>>>(Cp, x, mlp_norm_w + l * DMODEL, x, xn, 8);
        k_gu_part<<<dim3(FF / 64, 4, 4), 256, 0, stream>>>(
            xn, w_gate + (size_t)l * DMODEL * FF, w_up + (size_t)l * DMODEL * FF, GU);
        k_finish_silumul<<<NTOK * FF / 256, 256, 0, stream>>>(GU, g);
        k_mm_part<<<dim3(DMODEL / 64, 4, 12), 256, 0, stream>>>(
            g, w_down + (size_t)l * FF * DMODEL, Cp, FF, DMODEL, 128);
        if (l == 0) {
            k_finish_norm<<<NTOK, 256, 0, stream>>>(Cp, x, attn_norm_w + DMODEL, x, xn, 12);
        } else {
            // fused: states = rmsnorm(x_final, final_norm_w); H0 = rmsnorm(states, rc_norm_w)
            k_finish_norm2<<<NTOK, 256, 0, stream>>>(Cp, x, final_norm_w, rc_norm_w,
                                                     x, states, H, 12);
        }
    }

    // ---------- refinement steps (halt path stays f32) ----------
    float* scur = states;
    float* snxt = states2;
    for (int s = 0; s < NSTEPS; ++s) {
        k_mm_part<<<dim3(RCFF / 64, 4, 4), 256, 0, stream>>>(
            H + (size_t)s * NTOK * DMODEL, rc_w1, Cp, DMODEL, RCFF, 128);
        k_mm_finish<<<NTOK * RCFF / 256, 256, 0, stream>>>(
            Cp, nullptr, t1, NTOK * RCFF, NTOK * RCFF, 4, 1);
        k_mm_part<<<dim3(DMODEL / 64, 4, 16), 256, 0, stream>>>(
            t1, rc_w2, Cp, RCFF, DMODEL, 128);
        k_finish_norm<<<NTOK, 256, 0, stream>>>(
            Cp, scur, rc_norm_w, snxt, H + (size_t)(s + 1) * NTOK * DMODEL, 16);
        float* tmp = scur; scur = snxt; snxt = tmp;
    }

    // ---------- halt + ACT + A/B in one kernel ----------
    k_haltactab<<<NTOK, 256, 0, stream>>>(H, w_halt, b_halt,
                                          out + (size_t)NTOK * VOCAB,
                                          out + (size_t)NTOK * VOCAB + NTOK,
                                          Abf, Bbf);

    // ---------- final logits (MFMA 32x32x16 bf16, R13-exact) ----------
    k_logits_mfma<<<VOCAB / 64, 512, 0, stream>>>(Abf, Bbf, w_y, w_delta, out);
}